// Round 3
// baseline (533.674 us; speedup 1.0000x reference)
//
#include <hip/hip_runtime.h>
#include <hip/hip_bf16.h>

#define B_ 32
#define S_ 1024
#define D_ 512
#define PSTR 1048    // P row stride (bf16 elems)
#define PSTR1 1032   // fallback v1 stride

typedef __attribute__((ext_vector_type(8))) short short8;
typedef __attribute__((ext_vector_type(4))) float f32x4;

__device__ __forceinline__ unsigned short f2bf(float f) {
    unsigned u = __float_as_uint(f);
    u += 0x7FFFu + ((u >> 16) & 1u);   // round-to-nearest-even
    return (unsigned short)(u >> 16);
}
__device__ __forceinline__ float bf2f(unsigned short s) {
    return __uint_as_float(((unsigned)s) << 16);
}

// ===================== prep: Q -> QB bf16, row-major [B,S,D] =====================
__global__ __launch_bounds__(256) void prep_q(const float* __restrict__ Q,
                                              unsigned short* __restrict__ QB) {
    const size_t i = ((size_t)blockIdx.x * 256 + threadIdx.x) * 8;
    const float4 a = *reinterpret_cast<const float4*>(Q + i);
    const float4 c = *reinterpret_cast<const float4*>(Q + i + 4);
    short8 p;
    p[0]=(short)f2bf(a.x); p[1]=(short)f2bf(a.y); p[2]=(short)f2bf(a.z); p[3]=(short)f2bf(a.w);
    p[4]=(short)f2bf(c.x); p[5]=(short)f2bf(c.y); p[6]=(short)f2bf(c.z); p[7]=(short)f2bf(c.w);
    *reinterpret_cast<short8*>(QB + i) = p;
}

// ===================== prep: K -> KT bf16, fragment-native =====================
// KT[b][ds(16)][kcol(1024)][dquad(4)][8]
__global__ __launch_bounds__(256) void prep_k(const float* __restrict__ K,
                                              unsigned short* __restrict__ KT) {
    const int blk = blockIdx.x;          // 32*256 blocks: 4 rows x 512 d each
    const int b  = blk >> 8;
    const int r4 = blk & 255;
    const int t  = threadIdx.x;
    const int r  = t >> 6;               // 0..3
    const int d0 = (t & 63) * 8;
    const int s  = r4 * 4 + r;
    const float* src = K + ((size_t)(b * S_ + s)) * D_ + d0;
    const float4 a = *reinterpret_cast<const float4*>(src);
    const float4 c = *reinterpret_cast<const float4*>(src + 4);
    const int ds = d0 >> 5, dq = (d0 >> 3) & 3;
    short8 p;
    p[0]=(short)f2bf(a.x); p[1]=(short)f2bf(a.y); p[2]=(short)f2bf(a.z); p[3]=(short)f2bf(a.w);
    p[4]=(short)f2bf(c.x); p[5]=(short)f2bf(c.y); p[6]=(short)f2bf(c.z); p[7]=(short)f2bf(c.w);
    unsigned short* dst = KT + (size_t)b * 524288 + (((ds * 1024 + s) * 4 + dq) * 8);
    *reinterpret_cast<short8*>(dst) = p;
}

// ===================== prep: V -> VT bf16, transposed fragment-native =====================
// VT[b][kk(32)][dcol(512)][kquad(4)][8]
__global__ __launch_bounds__(256) void prep_v(const float* __restrict__ V,
                                              unsigned short* __restrict__ VT) {
    __shared__ float st[32 * 260];
    const int blk = blockIdx.x;          // 32*32*2 blocks
    const int b  = blk >> 6;
    const int kk = (blk >> 1) & 31;
    const int dh = blk & 1;
    const int t  = threadIdx.x;
    const int r0 = t >> 6;
    const int c4 = (t & 63) * 4;
    #pragma unroll
    for (int p = 0; p < 8; ++p) {
        const int s = r0 + p * 4;
        const float4 val = *reinterpret_cast<const float4*>(
            V + ((size_t)(b * S_ + kk * 32 + s)) * D_ + dh * 256 + c4);
        *reinterpret_cast<float4*>(&st[s * 260 + c4]) = val;
    }
    __syncthreads();
    const int dcol = t;
    unsigned short* dst = VT + (size_t)b * 524288 + ((kk * 512 + dh * 256 + dcol) * 4) * 8;
    #pragma unroll
    for (int kq = 0; kq < 4; ++kq) {
        short8 p;
        #pragma unroll
        for (int j = 0; j < 8; ++j) p[j] = (short)f2bf(st[(kq * 8 + j) * 260 + dcol]);
        *reinterpret_cast<short8*>(dst + kq * 8) = p;
    }
}

// ===================== main fused kernel: 32 q-rows / block, 8 waves, pipelined =====================
__global__ __launch_bounds__(512, 4)
void attn_main32(const unsigned short* __restrict__ QB, const unsigned short* __restrict__ KT,
                 const unsigned short* __restrict__ VT, const int* __restrict__ RM,
                 float* __restrict__ Out, float* __restrict__ Attn) {
    __shared__ short p_lds[32 * PSTR];   // 67072 B
    __shared__ float rm_f[1024];         // 4096 B  -> 2 blocks/CU

    const int tid  = threadIdx.x;
    const int lane = tid & 63;
    const int w    = tid >> 6;           // 0..7
    const int m    = lane & 15;
    const int quad = lane >> 4;

    const int work = ((int)blockIdx.x & 7) * 128 + ((int)blockIdx.x >> 3);
    const int b  = work >> 5;
    const int qt = work & 31;

    {
        const int2 mi = *reinterpret_cast<const int2*>(RM + b * S_ + tid * 2);
        rm_f[tid * 2]     = (float)mi.x;
        rm_f[tid * 2 + 1] = (float)mi.y;
    }

    // ---------------- Phase 1: raw scores = Q K^T (ping-pong pipelined) ----------------
    f32x4 acc1[2][8];
    #pragma unroll
    for (int mt = 0; mt < 2; ++mt)
        #pragma unroll
        for (int t = 0; t < 8; ++t) acc1[mt][t] = (f32x4){0.f, 0.f, 0.f, 0.f};

    const unsigned short* qb0 = QB + (size_t)b * (S_ * D_) + (size_t)(qt * 32 + m) * D_ + quad * 8;
    const unsigned short* qb1 = qb0 + 16 * D_;
    const unsigned short* kb  = KT + (size_t)b * 524288 + (w * 128 + m) * 32 + quad * 8;

    short8 kA[4], kB[4];
    short8 qa0, qa1, qn0, qn1;

    qa0 = *reinterpret_cast<const short8*>(qb0);
    qa1 = *reinterpret_cast<const short8*>(qb1);
    #pragma unroll
    for (int t = 0; t < 4; ++t) kA[t] = *reinterpret_cast<const short8*>(kb + t * 512);

    for (int ds = 0; ds < 16; ds += 2) {
        const unsigned short* k0 = kb + (size_t)ds * 32768;
        const unsigned short* k1 = k0 + 32768;
        const int dsn2 = (ds + 2 < 16) ? ds + 2 : 15;       // clamped dup at tail (harmless)
        const unsigned short* k2 = kb + (size_t)dsn2 * 32768;

        // ---- body A (ds): kA holds G0(ds), qa holds Q(ds) ----
        #pragma unroll
        for (int t = 0; t < 4; ++t) kB[t] = *reinterpret_cast<const short8*>(k0 + (4 + t) * 512);
        qn0 = *reinterpret_cast<const short8*>(qb0 + (ds + 1) * 32);
        qn1 = *reinterpret_cast<const short8*>(qb1 + (ds + 1) * 32);
        #pragma unroll
        for (int t = 0; t < 4; ++t) {
            acc1[0][t] = __builtin_amdgcn_mfma_f32_16x16x32_bf16(qa0, kA[t], acc1[0][t], 0, 0, 0);
            acc1[1][t] = __builtin_amdgcn_mfma_f32_16x16x32_bf16(qa1, kA[t], acc1[1][t], 0, 0, 0);
        }
        #pragma unroll
        for (int t = 0; t < 4; ++t) kA[t] = *reinterpret_cast<const short8*>(k1 + t * 512);
        #pragma unroll
        for (int t = 0; t < 4; ++t) {
            acc1[0][4+t] = __builtin_amdgcn_mfma_f32_16x16x32_bf16(qa0, kB[t], acc1[0][4+t], 0, 0, 0);
            acc1[1][4+t] = __builtin_amdgcn_mfma_f32_16x16x32_bf16(qa1, kB[t], acc1[1][4+t], 0, 0, 0);
        }

        // ---- body B (ds+1): kA holds G0(ds+1), qn holds Q(ds+1) ----
        #pragma unroll
        for (int t = 0; t < 4; ++t) kB[t] = *reinterpret_cast<const short8*>(k1 + (4 + t) * 512);
        qa0 = *reinterpret_cast<const short8*>(qb0 + dsn2 * 32);
        qa1 = *reinterpret_cast<const short8*>(qb1 + dsn2 * 32);
        #pragma unroll
        for (int t = 0; t < 4; ++t) {
            acc1[0][t] = __builtin_amdgcn_mfma_f32_16x16x32_bf16(qn0, kA[t], acc1[0][t], 0, 0, 0);
            acc1[1][t] = __builtin_amdgcn_mfma_f32_16x16x32_bf16(qn1, kA[t], acc1[1][t], 0, 0, 0);
        }
        #pragma unroll
        for (int t = 0; t < 4; ++t) kA[t] = *reinterpret_cast<const short8*>(k2 + t * 512);
        #pragma unroll
        for (int t = 0; t < 4; ++t) {
            acc1[0][4+t] = __builtin_amdgcn_mfma_f32_16x16x32_bf16(qn0, kB[t], acc1[0][4+t], 0, 0, 0);
            acc1[1][4+t] = __builtin_amdgcn_mfma_f32_16x16x32_bf16(qn1, kB[t], acc1[1][4+t], 0, 0, 0);
        }
    }

    #pragma unroll
    for (int mt = 0; mt < 2; ++mt)
        #pragma unroll
        for (int t = 0; t < 8; ++t) {
            const int col = w * 128 + t * 16 + m;
            #pragma unroll
            for (int r = 0; r < 4; ++r)
                p_lds[(mt * 16 + quad * 4 + r) * PSTR + col] = (short)f2bf(acc1[mt][t][r]);
        }
    __syncthreads();

    // ---------------- softmax (reference-faithful masked variant) ----------------
    {
        const int r  = tid >> 4;          // 0..31
        const int kc = tid & 15;
        const int qg = qt * 32 + r;
        const float rmq = rm_f[qg];
        const float inv_scale = 0.04419417382415922f;   // 1/sqrt(512)

        float4 sv[16];
        float mx = 0.0f;
        #pragma unroll
        for (int j = 0; j < 16; ++j) {
            const int k0 = 4 * kc + 64 * j;
            short4 s4 = *reinterpret_cast<const short4*>(&p_lds[r * PSTR + k0]);
            const float4 rmk = *reinterpret_cast<const float4*>(&rm_f[k0]);
            float s0 = bf2f((unsigned short)s4.x) * inv_scale;
            float s1 = bf2f((unsigned short)s4.y) * inv_scale;
            float s2 = bf2f((unsigned short)s4.z) * inv_scale;
            float s3 = bf2f((unsigned short)s4.w) * inv_scale;
            sv[j] = make_float4(s0, s1, s2, s3);
            if (rmq != 0.f) {
                if (rmk.x != 0.f && (k0+0) < qg) mx = fmaxf(mx, s0);
                if (rmk.y != 0.f && (k0+1) < qg) mx = fmaxf(mx, s1);
                if (rmk.z != 0.f && (k0+2) < qg) mx = fmaxf(mx, s2);
                if (rmk.w != 0.f && (k0+3) < qg) mx = fmaxf(mx, s3);
            }
        }
        #pragma unroll
        for (int off = 1; off < 16; off <<= 1) mx = fmaxf(mx, __shfl_xor(mx, off));

        float sum = 0.0f;
        #pragma unroll
        for (int j = 0; j < 16; ++j) {
            const int k0 = 4 * kc + 64 * j;
            const float4 rmk = *reinterpret_cast<const float4*>(&rm_f[k0]);
            float p0 = 0.f, p1 = 0.f, p2 = 0.f, p3 = 0.f;
            if (rmq != 0.f) {
                if (rmk.x != 0.f && (k0+0) < qg) p0 = __expf(sv[j].x - mx);
                if (rmk.y != 0.f && (k0+1) < qg) p1 = __expf(sv[j].y - mx);
                if (rmk.z != 0.f && (k0+2) < qg) p2 = __expf(sv[j].z - mx);
                if (rmk.w != 0.f && (k0+3) < qg) p3 = __expf(sv[j].w - mx);
            }
            sv[j] = make_float4(p0, p1, p2, p3);
            sum += (p0 + p1) + (p2 + p3);
        }
        #pragma unroll
        for (int off = 1; off < 16; off <<= 1) sum += __shfl_xor(sum, off);

        float den = sum + ((sum == 0.0f) ? 1.0f : 0.0f);
        const float invd = 1.0f / (den + 1e-20f);

        float* arow = Attn + ((size_t)(b * S_) + qg) * S_;
        #pragma unroll
        for (int j = 0; j < 16; ++j) {
            const int k0 = 4 * kc + 64 * j;
            float p0 = sv[j].x * invd, p1 = sv[j].y * invd;
            float p2 = sv[j].z * invd, p3 = sv[j].w * invd;
            *reinterpret_cast<float4*>(arow + k0) = make_float4(p0, p1, p2, p3);
            short4 pb;
            pb.x=(short)f2bf(p0); pb.y=(short)f2bf(p1); pb.z=(short)f2bf(p2); pb.w=(short)f2bf(p3);
            *reinterpret_cast<short4*>(&p_lds[r * PSTR + k0]) = pb;
        }
    }
    __syncthreads();

    // ---------------- Phase 2: Out = P V (ping-pong pipelined) ----------------
    f32x4 acc2[2][4];
    #pragma unroll
    for (int mt = 0; mt < 2; ++mt)
        #pragma unroll
        for (int f = 0; f < 4; ++f) acc2[mt][f] = (f32x4){0.f, 0.f, 0.f, 0.f};

    const unsigned short* vb = VT + (size_t)b * 524288 + m * 32 + quad * 8;
    const short* pr0 = &p_lds[m * PSTR + quad * 8];
    const short* pr1 = &p_lds[(16 + m) * PSTR + quad * 8];

    short8 vA[4], vB[4];
    short8 aA0, aA1, aB0, aB1;

    aA0 = *reinterpret_cast<const short8*>(pr0);
    aA1 = *reinterpret_cast<const short8*>(pr1);
    #pragma unroll
    for (int f = 0; f < 4; ++f)
        vA[f] = *reinterpret_cast<const short8*>(vb + (w * 4 + f) * 512);

    for (int kk = 0; kk < 32; kk += 2) {
        const unsigned short* v1 = vb + (size_t)(kk + 1) * 16384;
        const int kn2 = (kk + 2 < 32) ? kk + 2 : 31;        // clamped dup at tail
        const unsigned short* v2 = vb + (size_t)kn2 * 16384;

        // ---- body A (kk) ----
        aB0 = *reinterpret_cast<const short8*>(pr0 + (kk + 1) * 32);
        aB1 = *reinterpret_cast<const short8*>(pr1 + (kk + 1) * 32);
        #pragma unroll
        for (int f = 0; f < 4; ++f)
            vB[f] = *reinterpret_cast<const short8*>(v1 + (w * 4 + f) * 512);
        #pragma unroll
        for (int f = 0; f < 4; ++f) {
            acc2[0][f] = __builtin_amdgcn_mfma_f32_16x16x32_bf16(aA0, vA[f], acc2[0][f], 0, 0, 0);
            acc2[1][f] = __builtin_amdgcn_mfma_f32_16x16x32_bf16(aA1, vA[f], acc2[1][f], 0, 0, 0);
        }

        // ---- body B (kk+1) ----
        aA0 = *reinterpret_cast<const short8*>(pr0 + kn2 * 32);
        aA1 = *reinterpret_cast<const short8*>(pr1 + kn2 * 32);
        #pragma unroll
        for (int f = 0; f < 4; ++f)
            vA[f] = *reinterpret_cast<const short8*>(v2 + (w * 4 + f) * 512);
        #pragma unroll
        for (int f = 0; f < 4; ++f) {
            acc2[0][f] = __builtin_amdgcn_mfma_f32_16x16x32_bf16(aB0, vB[f], acc2[0][f], 0, 0, 0);
            acc2[1][f] = __builtin_amdgcn_mfma_f32_16x16x32_bf16(aB1, vB[f], acc2[1][f], 0, 0, 0);
        }
    }

    float* obase = Out + ((size_t)(b * S_ + qt * 32)) * D_;
    #pragma unroll
    for (int mt = 0; mt < 2; ++mt)
        #pragma unroll
        for (int f = 0; f < 4; ++f) {
            const int n0 = (w * 4 + f) * 16 + m;
            #pragma unroll
            for (int r = 0; r < 4; ++r)
                obase[(size_t)(mt * 16 + quad * 4 + r) * D_ + n0] = acc2[mt][f][r];
        }
}

// ===================== fallback: 16-row main (needs only KT+VT, 64 MB) =====================
__global__ __launch_bounds__(256, 4)
void attn_main(const float* __restrict__ Q, const unsigned short* __restrict__ KT,
               const unsigned short* __restrict__ VT, const int* __restrict__ RM,
               float* __restrict__ Out, float* __restrict__ Attn) {
    __shared__ short p_lds[16 * PSTR];
    __shared__ float rm_f[1024];

    const int tid  = threadIdx.x;
    const int lane = tid & 63;
    const int w    = tid >> 6;
    const int m    = lane & 15;
    const int quad = lane >> 4;

    const int work = ((int)blockIdx.x & 7) * 256 + ((int)blockIdx.x >> 3);
    const int b  = work >> 6;
    const int qt = work & 63;

    {
        const int4 mi = *reinterpret_cast<const int4*>(RM + b * S_ + tid * 4);
        float4 mf = make_float4((float)mi.x, (float)mi.y, (float)mi.z, (float)mi.w);
        *reinterpret_cast<float4*>(&rm_f[tid * 4]) = mf;
    }

    f32x4 acc1[16];
    #pragma unroll
    for (int t = 0; t < 16; ++t) acc1[t] = (f32x4){0.f, 0.f, 0.f, 0.f};

    const int kw0 = w * 256;
    const float* qbase = Q + ((size_t)(b * S_ + qt * 16 + m)) * D_ + quad * 8;
    const unsigned short* kb = KT + (size_t)b * 524288 + (kw0 + m) * 32 + quad * 8;

    for (int ds = 0; ds < 16; ++ds) {
        const float4 qa = *reinterpret_cast<const float4*>(qbase + ds * 32);
        const float4 qb = *reinterpret_cast<const float4*>(qbase + ds * 32 + 4);
        short8 af;
        af[0]=(short)f2bf(qa.x); af[1]=(short)f2bf(qa.y); af[2]=(short)f2bf(qa.z); af[3]=(short)f2bf(qa.w);
        af[4]=(short)f2bf(qb.x); af[5]=(short)f2bf(qb.y); af[6]=(short)f2bf(qb.z); af[7]=(short)f2bf(qb.w);
        const unsigned short* kds = kb + ds * 32768;
        #pragma unroll
        for (int t = 0; t < 16; ++t) {
            const short8 bf = *reinterpret_cast<const short8*>(kds + t * 512);
            acc1[t] = __builtin_amdgcn_mfma_f32_16x16x32_bf16(af, bf, acc1[t], 0, 0, 0);
        }
    }
    #pragma unroll
    for (int t = 0; t < 16; ++t) {
        const int col = kw0 + t * 16 + m;
        #pragma unroll
        for (int r = 0; r < 4; ++r)
            p_lds[(quad * 4 + r) * PSTR + col] = (short)f2bf(acc1[t][r]);
    }
    __syncthreads();

    {
        const int r  = tid >> 4;
        const int kc = tid & 15;
        const int qg = qt * 16 + r;
        const float rmq = rm_f[qg];
        const float inv_scale = 0.04419417382415922f;

        float4 sv[16];
        float mx = 0.0f;
        #pragma unroll
        for (int j = 0; j < 16; ++j) {
            const int k0 = 4 * kc + 64 * j;
            short4 s4 = *reinterpret_cast<const short4*>(&p_lds[r * PSTR + k0]);
            const float4 rmk = *reinterpret_cast<const float4*>(&rm_f[k0]);
            float s0 = bf2f((unsigned short)s4.x) * inv_scale;
            float s1 = bf2f((unsigned short)s4.y) * inv_scale;
            float s2 = bf2f((unsigned short)s4.z) * inv_scale;
            float s3 = bf2f((unsigned short)s4.w) * inv_scale;
            sv[j] = make_float4(s0, s1, s2, s3);
            if (rmq != 0.f) {
                if (rmk.x != 0.f && (k0+0) < qg) mx = fmaxf(mx, s0);
                if (rmk.y != 0.f && (k0+1) < qg) mx = fmaxf(mx, s1);
                if (rmk.z != 0.f && (k0+2) < qg) mx = fmaxf(mx, s2);
                if (rmk.w != 0.f && (k0+3) < qg) mx = fmaxf(mx, s3);
            }
        }
        #pragma unroll
        for (int off = 1; off < 16; off <<= 1) mx = fmaxf(mx, __shfl_xor(mx, off));

        float sum = 0.0f;
        #pragma unroll
        for (int j = 0; j < 16; ++j) {
            const int k0 = 4 * kc + 64 * j;
            const float4 rmk = *reinterpret_cast<const float4*>(&rm_f[k0]);
            float p0 = 0.f, p1 = 0.f, p2 = 0.f, p3 = 0.f;
            if (rmq != 0.f) {
                if (rmk.x != 0.f && (k0+0) < qg) p0 = __expf(sv[j].x - mx);
                if (rmk.y != 0.f && (k0+1) < qg) p1 = __expf(sv[j].y - mx);
                if (rmk.z != 0.f && (k0+2) < qg) p2 = __expf(sv[j].z - mx);
                if (rmk.w != 0.f && (k0+3) < qg) p3 = __expf(sv[j].w - mx);
            }
            sv[j] = make_float4(p0, p1, p2, p3);
            sum += (p0 + p1) + (p2 + p3);
        }
        #pragma unroll
        for (int off = 1; off < 16; off <<= 1) sum += __shfl_xor(sum, off);

        float den = sum + ((sum == 0.0f) ? 1.0f : 0.0f);
        const float invd = 1.0f / (den + 1e-20f);

        float* arow = Attn + ((size_t)(b * S_) + qg) * S_;
        #pragma unroll
        for (int j = 0; j < 16; ++j) {
            const int k0 = 4 * kc + 64 * j;
            float p0 = sv[j].x * invd, p1 = sv[j].y * invd;
            float p2 = sv[j].z * invd, p3 = sv[j].w * invd;
            *reinterpret_cast<float4*>(arow + k0) = make_float4(p0, p1, p2, p3);
            short4 pb;
            pb.x=(short)f2bf(p0); pb.y=(short)f2bf(p1); pb.z=(short)f2bf(p2); pb.w=(short)f2bf(p3);
            *reinterpret_cast<short4*>(&p_lds[r * PSTR + k0]) = pb;
        }
    }
    __syncthreads();

    f32x4 acc2[8];
    #pragma unroll
    for (int i = 0; i < 8; ++i) acc2[i] = (f32x4){0.f, 0.f, 0.f, 0.f};

    const unsigned short* vb = VT + (size_t)b * 524288 + m * 32 + quad * 8;
    for (int kk = 0; kk < 32; ++kk) {
        const short8 af = *reinterpret_cast<const short8*>(
            &p_lds[m * PSTR + kk * 32 + quad * 8]);
        const unsigned short* vkk = vb + kk * 16384;
        #pragma unroll
        for (int f = 0; f < 8; ++f) {
            const int dtile = f * 4 + w;
            const short8 bf = *reinterpret_cast<const short8*>(vkk + dtile * 512);
            acc2[f] = __builtin_amdgcn_mfma_f32_16x16x32_bf16(af, bf, acc2[f], 0, 0, 0);
        }
    }

    float* obase = Out + ((size_t)(b * S_ + qt * 16)) * D_;
    #pragma unroll
    for (int f = 0; f < 8; ++f) {
        const int n0 = (f * 4 + w) * 16 + m;
        #pragma unroll
        for (int r = 0; r < 4; ++r)
            obase[(size_t)(quad * 4 + r) * D_ + n0] = acc2[f][r];
    }
}

// ===================== fallback v1 (used only if ws too small) =====================
__global__ __launch_bounds__(256, 3)
void attn_fused_v1(const float* __restrict__ Q, const float* __restrict__ K,
                   const float* __restrict__ V, const int* __restrict__ RM,
                   float* __restrict__ Out, float* __restrict__ Attn) {
    __shared__ short p_lds[16 * PSTR1];
    __shared__ short vt_lds[8192];
    float* rm_f = reinterpret_cast<float*>(vt_lds);

    const int tid  = threadIdx.x;
    const int lane = tid & 63;
    const int w    = tid >> 6;
    const int m    = lane & 15;
    const int quad = lane >> 4;

    const int work = ((int)blockIdx.x & 7) * 256 + ((int)blockIdx.x >> 3);
    const int b  = work >> 6;
    const int qt = work & 63;

    {
        const int4 mi = *reinterpret_cast<const int4*>(RM + b * S_ + tid * 4);
        float4 mf = make_float4((float)mi.x, (float)mi.y, (float)mi.z, (float)mi.w);
        *reinterpret_cast<float4*>(&rm_f[tid * 4]) = mf;
    }

    f32x4 acc1[16];
    #pragma unroll
    for (int t = 0; t < 16; ++t) acc1[t] = (f32x4){0.f, 0.f, 0.f, 0.f};

    const int kw0 = w * 256;
    const float* qbase = Q + ((size_t)(b * S_ + qt * 16 + m)) * D_ + quad * 8;
    const float* kbase = K + ((size_t)(b * S_ + kw0 + m)) * D_ + quad * 8;

    for (int ds = 0; ds < 16; ++ds) {
        const float4 qa = *reinterpret_cast<const float4*>(qbase + ds * 32);
        const float4 qb = *reinterpret_cast<const float4*>(qbase + ds * 32 + 4);
        short8 af;
        af[0]=(short)f2bf(qa.x); af[1]=(short)f2bf(qa.y); af[2]=(short)f2bf(qa.z); af[3]=(short)f2bf(qa.w);
        af[4]=(short)f2bf(qb.x); af[5]=(short)f2bf(qb.y); af[6]=(short)f2bf(qb.z); af[7]=(short)f2bf(qb.w);
        #pragma unroll
        for (int t = 0; t < 16; ++t) {
            const float* kr = kbase + (size_t)t * 16 * D_ + ds * 32;
            const float4 ka = *reinterpret_cast<const float4*>(kr);
            const float4 kb = *reinterpret_cast<const float4*>(kr + 4);
            short8 bf;
            bf[0]=(short)f2bf(ka.x); bf[1]=(short)f2bf(ka.y); bf[2]=(short)f2bf(ka.z); bf[3]=(short)f2bf(ka.w);
            bf[4]=(short)f2bf(kb.x); bf[5]=(short)f2bf(kb.y); bf[6]=(short)f2bf(kb.z); bf[7]=(short)f2bf(kb.w);
            acc1[t] = __builtin_amdgcn_mfma_f32_16x16x32_bf16(af, bf, acc1[t], 0, 0, 0);
        }
    }
    #pragma unroll
    for (int t = 0; t < 16; ++t) {
        const int col = kw0 + t * 16 + m;
        #pragma unroll
        for (int r = 0; r < 4; ++r)
            p_lds[(quad * 4 + r) * PSTR1 + col] = (short)f2bf(acc1[t][r]);
    }
    __syncthreads();

    {
        const int r  = tid >> 4;
        const int kc = tid & 15;
        const int qg = qt * 16 + r;
        const float rmq = rm_f[qg];
        const float inv_scale = 0.04419417382415922f;

        float4 sv[16];
        float mx = 0.0f;
        #pragma unroll
        for (int j = 0; j < 16; ++j) {
            const int k0 = 4 * kc + 64 * j;
            short4 s4 = *reinterpret_cast<const short4*>(&p_lds[r * PSTR1 + k0]);
            float s0 = bf2f((unsigned short)s4.x) * inv_scale;
            float s1 = bf2f((unsigned short)s4.y) * inv_scale;
            float s2 = bf2f((unsigned short)s4.z) * inv_scale;
            float s3 = bf2f((unsigned short)s4.w) * inv_scale;
            sv[j] = make_float4(s0, s1, s2, s3);
            if (rmq != 0.f) {
                if (rm_f[k0+0] != 0.f && (k0+0) < qg) mx = fmaxf(mx, s0);
                if (rm_f[k0+1] != 0.f && (k0+1) < qg) mx = fmaxf(mx, s1);
                if (rm_f[k0+2] != 0.f && (k0+2) < qg) mx = fmaxf(mx, s2);
                if (rm_f[k0+3] != 0.f && (k0+3) < qg) mx = fmaxf(mx, s3);
            }
        }
        #pragma unroll
        for (int off = 1; off < 16; off <<= 1) mx = fmaxf(mx, __shfl_xor(mx, off));

        float sum = 0.0f;
        #pragma unroll
        for (int j = 0; j < 16; ++j) {
            const int k0 = 4 * kc + 64 * j;
            float p0 = 0.f, p1 = 0.f, p2 = 0.f, p3 = 0.f;
            if (rmq != 0.f) {
                if (rm_f[k0+0] != 0.f && (k0+0) < qg) p0 = __expf(sv[j].x - mx);
                if (rm_f[k0+1] != 0.f && (k0+1) < qg) p1 = __expf(sv[j].y - mx);
                if (rm_f[k0+2] != 0.f && (k0+2) < qg) p2 = __expf(sv[j].z - mx);
                if (rm_f[k0+3] != 0.f && (k0+3) < qg) p3 = __expf(sv[j].w - mx);
            }
            sv[j] = make_float4(p0, p1, p2, p3);
            sum += (p0 + p1) + (p2 + p3);
        }
        #pragma unroll
        for (int off = 1; off < 16; off <<= 1) sum += __shfl_xor(sum, off);

        float den = sum + ((sum == 0.0f) ? 1.0f : 0.0f);
        const float invd = 1.0f / (den + 1e-20f);

        float* arow = Attn + ((size_t)(b * S_) + qg) * S_;
        #pragma unroll
        for (int j = 0; j < 16; ++j) {
            const int k0 = 4 * kc + 64 * j;
            float p0 = sv[j].x * invd, p1 = sv[j].y * invd;
            float p2 = sv[j].z * invd, p3 = sv[j].w * invd;
            *reinterpret_cast<float4*>(arow + k0) = make_float4(p0, p1, p2, p3);
            short4 pb;
            pb.x=(short)f2bf(p0); pb.y=(short)f2bf(p1); pb.z=(short)f2bf(p2); pb.w=(short)f2bf(p3);
            *reinterpret_cast<short4*>(&p_lds[r * PSTR1 + k0]) = pb;
        }
    }
    __syncthreads();

    f32x4 acc2[8];
    #pragma unroll
    for (int i = 0; i < 8; ++i) acc2[i] = (f32x4){0.f, 0.f, 0.f, 0.f};

    for (int kk = 0; kk < 32; ++kk) {
        const short8 af = *reinterpret_cast<const short8*>(
            &p_lds[m * PSTR1 + kk * 32 + quad * 8]);
        #pragma unroll
        for (int nh = 0; nh < 2; ++nh) {
            __syncthreads();
            {
                const int nl0 = tid & 63;
                const int qq0 = tid >> 6;
                #pragma unroll
                for (int i = 0; i < 8; ++i) {
                    const int nl = nl0 + 64 * (i & 3);
                    const int qq = qq0 + 4 * (i >> 2);
                    const float* src = V + ((size_t)(b * S_ + kk * 32 + qq * 4)) * D_
                                         + nh * 256 + nl;
                    const float v0 = src[0];
                    const float v1 = src[D_];
                    const float v2 = src[2 * D_];
                    const float v3 = src[3 * D_];
                    const int g  = (nl >> 1) & 3;
                    const int dw = nl * 16 + 4 * ((qq >> 1) ^ g) + 2 * (qq & 1);
                    short4 pk;
                    pk.x=(short)f2bf(v0); pk.y=(short)f2bf(v1);
                    pk.z=(short)f2bf(v2); pk.w=(short)f2bf(v3);
                    *reinterpret_cast<short4*>(&vt_lds[dw * 2]) = pk;
                }
            }
            __syncthreads();
            #pragma unroll
            for (int f = 0; f < 4; ++f) {
                const int nloc = (w + 4 * f) * 16 + m;
                const int g  = (nloc >> 1) & 3;
                const int dw = nloc * 16 + 4 * (quad ^ g);
                const short8 bf = *reinterpret_cast<const short8*>(&vt_lds[dw * 2]);
                acc2[nh * 4 + f] = __builtin_amdgcn_mfma_f32_16x16x32_bf16(af, bf, acc2[nh * 4 + f], 0, 0, 0);
            }
        }
    }

    float* obase = Out + ((size_t)(b * S_ + qt * 16)) * D_;
    #pragma unroll
    for (int nh = 0; nh < 2; ++nh) {
        #pragma unroll
        for (int f = 0; f < 4; ++f) {
            const int n0 = nh * 256 + (w + 4 * f) * 16 + m;
            #pragma unroll
            for (int r = 0; r < 4; ++r)
                obase[(size_t)(quad * 4 + r) * D_ + n0] = acc2[nh * 4 + f][r];
        }
    }
}

extern "C" void kernel_launch(void* const* d_in, const int* in_sizes, int n_in,
                              void* d_out, int out_size, void* d_ws, size_t ws_size,
                              hipStream_t stream) {
    (void)in_sizes; (void)n_in; (void)out_size;
    const float* q  = (const float*)d_in[0];
    const float* k  = (const float*)d_in[1];
    const float* v  = (const float*)d_in[2];
    const int*   rm = (const int*)d_in[3];
    float* out  = (float*)d_out;
    float* attn = out + (size_t)B_ * S_ * D_;

    const size_t buf_bytes = (size_t)B_ * 524288 * 2;    // 32 MB each
    const size_t need3 = 3 * buf_bytes;                  // KT + VT + QB = 96 MB
    const size_t need2 = 2 * buf_bytes;                  // KT + VT = 64 MB
    if (ws_size >= need3) {
        unsigned short* KT = (unsigned short*)d_ws;
        unsigned short* VT = KT + (size_t)B_ * 524288;
        unsigned short* QB = VT + (size_t)B_ * 524288;
        prep_q<<<dim3(8192), dim3(256), 0, stream>>>(q, QB);
        prep_k<<<dim3(B_ * 256), dim3(256), 0, stream>>>(k, KT);
        prep_v<<<dim3(B_ * 64), dim3(256), 0, stream>>>(v, VT);
        attn_main32<<<dim3(B_ * (S_ / 32)), dim3(512), 0, stream>>>(QB, KT, VT, rm, out, attn);
    } else if (ws_size >= need2) {
        unsigned short* KT = (unsigned short*)d_ws;
        unsigned short* VT = KT + (size_t)B_ * 524288;
        prep_k<<<dim3(B_ * 256), dim3(256), 0, stream>>>(k, KT);
        prep_v<<<dim3(B_ * 64), dim3(256), 0, stream>>>(v, VT);
        attn_main<<<dim3(B_ * (S_ / 16)), dim3(256), 0, stream>>>(q, KT, VT, rm, out, attn);
    } else {
        attn_fused_v1<<<dim3(B_ * (S_ / 16)), dim3(256), 0, stream>>>(q, k, v, rm, out, attn);
    }
}

// Round 4
// 526.818 us; speedup vs baseline: 1.0130x; 1.0130x over previous
//
#include <hip/hip_runtime.h>
#include <hip/hip_bf16.h>

#define B_ 32
#define S_ 1024
#define D_ 512
#define PSTR 1048    // P row stride (bf16 elems)
#define PSTR1 1032   // fallback v1 stride

typedef __attribute__((ext_vector_type(8))) short short8;
typedef __attribute__((ext_vector_type(4))) float f32x4;

__device__ __forceinline__ unsigned short f2bf(float f) {
    unsigned u = __float_as_uint(f);
    u += 0x7FFFu + ((u >> 16) & 1u);   // round-to-nearest-even
    return (unsigned short)(u >> 16);
}
__device__ __forceinline__ float bf2f(unsigned short s) {
    return __uint_as_float(((unsigned)s) << 16);
}

// ===================== prep: K -> KT bf16, fragment-native =====================
// KT[b][ds(16)][kcol(1024)][dquad(4)][8]
// store: lanes 0..3 cover dq 0..3 of one (ds,s) -> full 64B lines.
__global__ __launch_bounds__(256) void prep_k(const float* __restrict__ K,
                                              unsigned short* __restrict__ KT) {
    const int blk = blockIdx.x;          // 32*256 blocks: 4 rows x 512 d each
    const int b  = blk >> 8;
    const int r4 = blk & 255;
    const int t  = threadIdx.x;
    const int r  = t >> 6;               // 0..3
    const int d0 = (t & 63) * 8;
    const int s  = r4 * 4 + r;
    const float* src = K + ((size_t)(b * S_ + s)) * D_ + d0;
    const float4 a = *reinterpret_cast<const float4*>(src);
    const float4 c = *reinterpret_cast<const float4*>(src + 4);
    const int ds = d0 >> 5, dq = (d0 >> 3) & 3;
    short8 p;
    p[0]=(short)f2bf(a.x); p[1]=(short)f2bf(a.y); p[2]=(short)f2bf(a.z); p[3]=(short)f2bf(a.w);
    p[4]=(short)f2bf(c.x); p[5]=(short)f2bf(c.y); p[6]=(short)f2bf(c.z); p[7]=(short)f2bf(c.w);
    unsigned short* dst = KT + (size_t)b * 524288 + (((ds * 1024 + s) * 4 + dq) * 8);
    *reinterpret_cast<short8*>(dst) = p;
}

// ===================== prep: V -> VT bf16, transposed fragment-native =====================
// VT[b][kk(32)][dcol(512)][kquad(4)][8]
// store restructured: lane l -> dcol = l>>2, kq = l&3  =>  each wave writes 1KB contiguous.
__global__ __launch_bounds__(256) void prep_v(const float* __restrict__ V,
                                              unsigned short* __restrict__ VT) {
    __shared__ float st[32 * 261];       // pad 261: LDS read conflicts <= 2-way
    const int blk = blockIdx.x;          // 32*32*2 blocks
    const int b  = blk >> 6;
    const int kk = (blk >> 1) & 31;
    const int dh = blk & 1;
    const int t  = threadIdx.x;
    const int r0 = t >> 6;
    const int c4 = (t & 63) * 4;
    #pragma unroll
    for (int p = 0; p < 8; ++p) {
        const int s = r0 + p * 4;
        const float4 val = *reinterpret_cast<const float4*>(
            V + ((size_t)(b * S_ + kk * 32 + s)) * D_ + dh * 256 + c4);
        *reinterpret_cast<float4*>(&st[s * 261 + c4]) = val;
    }
    __syncthreads();
    const int kq = t & 3;
    #pragma unroll
    for (int pass = 0; pass < 4; ++pass) {
        const int dcol = (t >> 2) + pass * 64;   // local 0..255
        short8 p;
        #pragma unroll
        for (int j = 0; j < 8; ++j) p[j] = (short)f2bf(st[(kq * 8 + j) * 261 + dcol]);
        unsigned short* dst = VT + (size_t)b * 524288
            + (((size_t)(kk * 512 + dh * 256 + dcol) * 4 + kq) * 8);
        *reinterpret_cast<short8*>(dst) = p;
    }
}

// ===================== main fused kernel: 32 q-rows / block, 8 waves =====================
__global__ __launch_bounds__(512, 4)
void attn_main32(const float* __restrict__ Q, const unsigned short* __restrict__ KT,
                 const unsigned short* __restrict__ VT, const int* __restrict__ RM,
                 float* __restrict__ Out, float* __restrict__ Attn) {
    __shared__ short p_lds[32 * PSTR];   // 67072 B
    __shared__ float rm_f[1024];         // 4096 B  -> 2 blocks/CU

    const int tid  = threadIdx.x;
    const int lane = tid & 63;
    const int w    = tid >> 6;           // 0..7
    const int m    = lane & 15;
    const int quad = lane >> 4;

    const int work = ((int)blockIdx.x & 7) * 128 + ((int)blockIdx.x >> 3);
    const int b  = work >> 5;
    const int qt = work & 31;

    {
        const int2 mi = *reinterpret_cast<const int2*>(RM + b * S_ + tid * 2);
        rm_f[tid * 2]     = (float)mi.x;
        rm_f[tid * 2 + 1] = (float)mi.y;
    }

    // ---------------- Phase 1: raw scores = Q K^T (round-2 structure, fp32 Q) ----------------
    f32x4 acc1[2][8];
    #pragma unroll
    for (int mt = 0; mt < 2; ++mt)
        #pragma unroll
        for (int t = 0; t < 8; ++t) acc1[mt][t] = (f32x4){0.f, 0.f, 0.f, 0.f};

    const float* qb0 = Q + ((size_t)(b * S_ + qt * 32 + m)) * D_ + quad * 8;
    const float* qb1 = qb0 + 16 * D_;
    const unsigned short* kb = KT + (size_t)b * 524288 + (w * 128 + m) * 32 + quad * 8;

    for (int ds = 0; ds < 16; ++ds) {
        const float4 qa = *reinterpret_cast<const float4*>(qb0 + ds * 32);
        const float4 qc = *reinterpret_cast<const float4*>(qb0 + ds * 32 + 4);
        const float4 qd = *reinterpret_cast<const float4*>(qb1 + ds * 32);
        const float4 qe = *reinterpret_cast<const float4*>(qb1 + ds * 32 + 4);
        short8 a0, a1;
        a0[0]=(short)f2bf(qa.x); a0[1]=(short)f2bf(qa.y); a0[2]=(short)f2bf(qa.z); a0[3]=(short)f2bf(qa.w);
        a0[4]=(short)f2bf(qc.x); a0[5]=(short)f2bf(qc.y); a0[6]=(short)f2bf(qc.z); a0[7]=(short)f2bf(qc.w);
        a1[0]=(short)f2bf(qd.x); a1[1]=(short)f2bf(qd.y); a1[2]=(short)f2bf(qd.z); a1[3]=(short)f2bf(qd.w);
        a1[4]=(short)f2bf(qe.x); a1[5]=(short)f2bf(qe.y); a1[6]=(short)f2bf(qe.z); a1[7]=(short)f2bf(qe.w);
        const unsigned short* kds = kb + ds * 32768;
        #pragma unroll
        for (int t = 0; t < 8; ++t) {
            const short8 bf = *reinterpret_cast<const short8*>(kds + t * 512);
            acc1[0][t] = __builtin_amdgcn_mfma_f32_16x16x32_bf16(a0, bf, acc1[0][t], 0, 0, 0);
            acc1[1][t] = __builtin_amdgcn_mfma_f32_16x16x32_bf16(a1, bf, acc1[1][t], 0, 0, 0);
        }
    }
    #pragma unroll
    for (int mt = 0; mt < 2; ++mt)
        #pragma unroll
        for (int t = 0; t < 8; ++t) {
            const int col = w * 128 + t * 16 + m;
            #pragma unroll
            for (int r = 0; r < 4; ++r)
                p_lds[(mt * 16 + quad * 4 + r) * PSTR + col] = (short)f2bf(acc1[mt][t][r]);
        }
    __syncthreads();

    // ---------------- softmax (reference-faithful masked variant) ----------------
    {
        const int r  = tid >> 4;          // 0..31
        const int kc = tid & 15;
        const int qg = qt * 32 + r;
        const float rmq = rm_f[qg];
        const float inv_scale = 0.04419417382415922f;   // 1/sqrt(512)

        float4 sv[16];
        float mx = 0.0f;
        #pragma unroll
        for (int j = 0; j < 16; ++j) {
            const int k0 = 4 * kc + 64 * j;
            short4 s4 = *reinterpret_cast<const short4*>(&p_lds[r * PSTR + k0]);
            const float4 rmk = *reinterpret_cast<const float4*>(&rm_f[k0]);
            float s0 = bf2f((unsigned short)s4.x) * inv_scale;
            float s1 = bf2f((unsigned short)s4.y) * inv_scale;
            float s2 = bf2f((unsigned short)s4.z) * inv_scale;
            float s3 = bf2f((unsigned short)s4.w) * inv_scale;
            sv[j] = make_float4(s0, s1, s2, s3);
            if (rmq != 0.f) {
                if (rmk.x != 0.f && (k0+0) < qg) mx = fmaxf(mx, s0);
                if (rmk.y != 0.f && (k0+1) < qg) mx = fmaxf(mx, s1);
                if (rmk.z != 0.f && (k0+2) < qg) mx = fmaxf(mx, s2);
                if (rmk.w != 0.f && (k0+3) < qg) mx = fmaxf(mx, s3);
            }
        }
        #pragma unroll
        for (int off = 1; off < 16; off <<= 1) mx = fmaxf(mx, __shfl_xor(mx, off));

        float sum = 0.0f;
        #pragma unroll
        for (int j = 0; j < 16; ++j) {
            const int k0 = 4 * kc + 64 * j;
            const float4 rmk = *reinterpret_cast<const float4*>(&rm_f[k0]);
            float p0 = 0.f, p1 = 0.f, p2 = 0.f, p3 = 0.f;
            if (rmq != 0.f) {
                if (rmk.x != 0.f && (k0+0) < qg) p0 = __expf(sv[j].x - mx);
                if (rmk.y != 0.f && (k0+1) < qg) p1 = __expf(sv[j].y - mx);
                if (rmk.z != 0.f && (k0+2) < qg) p2 = __expf(sv[j].z - mx);
                if (rmk.w != 0.f && (k0+3) < qg) p3 = __expf(sv[j].w - mx);
            }
            sv[j] = make_float4(p0, p1, p2, p3);
            sum += (p0 + p1) + (p2 + p3);
        }
        #pragma unroll
        for (int off = 1; off < 16; off <<= 1) sum += __shfl_xor(sum, off);

        float den = sum + ((sum == 0.0f) ? 1.0f : 0.0f);
        const float invd = 1.0f / (den + 1e-20f);

        float* arow = Attn + ((size_t)(b * S_) + qg) * S_;
        #pragma unroll
        for (int j = 0; j < 16; ++j) {
            const int k0 = 4 * kc + 64 * j;
            float p0 = sv[j].x * invd, p1 = sv[j].y * invd;
            float p2 = sv[j].z * invd, p3 = sv[j].w * invd;
            *reinterpret_cast<float4*>(arow + k0) = make_float4(p0, p1, p2, p3);
            short4 pb;
            pb.x=(short)f2bf(p0); pb.y=(short)f2bf(p1); pb.z=(short)f2bf(p2); pb.w=(short)f2bf(p3);
            *reinterpret_cast<short4*>(&p_lds[r * PSTR + k0]) = pb;
        }
    }
    __syncthreads();

    // ---------------- Phase 2: Out = P V (4-buffer, 3-ahead prefetch rotation) ----------------
    f32x4 acc2[2][4];
    #pragma unroll
    for (int mt = 0; mt < 2; ++mt)
        #pragma unroll
        for (int f = 0; f < 4; ++f) acc2[mt][f] = (f32x4){0.f, 0.f, 0.f, 0.f};

    const unsigned short* vb = VT + (size_t)b * 524288 + m * 32 + quad * 8;
    const short* pr0 = &p_lds[m * PSTR + quad * 8];
    const short* pr1 = &p_lds[(16 + m) * PSTR + quad * 8];

#define LOADV(dst, kkk) do {                                                        \
    const unsigned short* vk_ = vb + (size_t)(kkk) * 16384;                         \
    dst[0] = *reinterpret_cast<const short8*>(vk_ + (w * 4 + 0) * 512);             \
    dst[1] = *reinterpret_cast<const short8*>(vk_ + (w * 4 + 1) * 512);             \
    dst[2] = *reinterpret_cast<const short8*>(vk_ + (w * 4 + 2) * 512);             \
    dst[3] = *reinterpret_cast<const short8*>(vk_ + (w * 4 + 3) * 512);             \
} while (0)

#define CONSUME(buf, kkk) do {                                                      \
    const short8 a0_ = *reinterpret_cast<const short8*>(pr0 + (kkk) * 32);          \
    const short8 a1_ = *reinterpret_cast<const short8*>(pr1 + (kkk) * 32);          \
    acc2[0][0] = __builtin_amdgcn_mfma_f32_16x16x32_bf16(a0_, buf[0], acc2[0][0], 0, 0, 0); \
    acc2[1][0] = __builtin_amdgcn_mfma_f32_16x16x32_bf16(a1_, buf[0], acc2[1][0], 0, 0, 0); \
    acc2[0][1] = __builtin_amdgcn_mfma_f32_16x16x32_bf16(a0_, buf[1], acc2[0][1], 0, 0, 0); \
    acc2[1][1] = __builtin_amdgcn_mfma_f32_16x16x32_bf16(a1_, buf[1], acc2[1][1], 0, 0, 0); \
    acc2[0][2] = __builtin_amdgcn_mfma_f32_16x16x32_bf16(a0_, buf[2], acc2[0][2], 0, 0, 0); \
    acc2[1][2] = __builtin_amdgcn_mfma_f32_16x16x32_bf16(a1_, buf[2], acc2[1][2], 0, 0, 0); \
    acc2[0][3] = __builtin_amdgcn_mfma_f32_16x16x32_bf16(a0_, buf[3], acc2[0][3], 0, 0, 0); \
    acc2[1][3] = __builtin_amdgcn_mfma_f32_16x16x32_bf16(a1_, buf[3], acc2[1][3], 0, 0, 0); \
} while (0)

    short8 v0[4], v1[4], v2[4], v3[4];
    LOADV(v0, 0); LOADV(v1, 1); LOADV(v2, 2); LOADV(v3, 3);

    #pragma unroll
    for (int kt = 0; kt < 32; kt += 4) {
        CONSUME(v0, kt);
        LOADV(v0, (kt + 4 < 32) ? kt + 4 : 31);
        CONSUME(v1, kt + 1);
        LOADV(v1, (kt + 5 < 32) ? kt + 5 : 31);
        CONSUME(v2, kt + 2);
        LOADV(v2, (kt + 6 < 32) ? kt + 6 : 31);
        CONSUME(v3, kt + 3);
        LOADV(v3, (kt + 7 < 32) ? kt + 7 : 31);
    }
#undef LOADV
#undef CONSUME

    float* obase = Out + ((size_t)(b * S_ + qt * 32)) * D_;
    #pragma unroll
    for (int mt = 0; mt < 2; ++mt)
        #pragma unroll
        for (int f = 0; f < 4; ++f) {
            const int n0 = (w * 4 + f) * 16 + m;
            #pragma unroll
            for (int r = 0; r < 4; ++r)
                obase[(size_t)(mt * 16 + quad * 4 + r) * D_ + n0] = acc2[mt][f][r];
        }
}

// ===================== fallback v1 (used only if ws too small) =====================
__global__ __launch_bounds__(256, 3)
void attn_fused_v1(const float* __restrict__ Q, const float* __restrict__ K,
                   const float* __restrict__ V, const int* __restrict__ RM,
                   float* __restrict__ Out, float* __restrict__ Attn) {
    __shared__ short p_lds[16 * PSTR1];
    __shared__ short vt_lds[8192];
    float* rm_f = reinterpret_cast<float*>(vt_lds);

    const int tid  = threadIdx.x;
    const int lane = tid & 63;
    const int w    = tid >> 6;
    const int m    = lane & 15;
    const int quad = lane >> 4;

    const int work = ((int)blockIdx.x & 7) * 256 + ((int)blockIdx.x >> 3);
    const int b  = work >> 6;
    const int qt = work & 63;

    {
        const int4 mi = *reinterpret_cast<const int4*>(RM + b * S_ + tid * 4);
        float4 mf = make_float4((float)mi.x, (float)mi.y, (float)mi.z, (float)mi.w);
        *reinterpret_cast<float4*>(&rm_f[tid * 4]) = mf;
    }

    f32x4 acc1[16];
    #pragma unroll
    for (int t = 0; t < 16; ++t) acc1[t] = (f32x4){0.f, 0.f, 0.f, 0.f};

    const int kw0 = w * 256;
    const float* qbase = Q + ((size_t)(b * S_ + qt * 16 + m)) * D_ + quad * 8;
    const float* kbase = K + ((size_t)(b * S_ + kw0 + m)) * D_ + quad * 8;

    for (int ds = 0; ds < 16; ++ds) {
        const float4 qa = *reinterpret_cast<const float4*>(qbase + ds * 32);
        const float4 qb = *reinterpret_cast<const float4*>(qbase + ds * 32 + 4);
        short8 af;
        af[0]=(short)f2bf(qa.x); af[1]=(short)f2bf(qa.y); af[2]=(short)f2bf(qa.z); af[3]=(short)f2bf(qa.w);
        af[4]=(short)f2bf(qb.x); af[5]=(short)f2bf(qb.y); af[6]=(short)f2bf(qb.z); af[7]=(short)f2bf(qb.w);
        #pragma unroll
        for (int t = 0; t < 16; ++t) {
            const float* kr = kbase + (size_t)t * 16 * D_ + ds * 32;
            const float4 ka = *reinterpret_cast<const float4*>(kr);
            const float4 kb = *reinterpret_cast<const float4*>(kr + 4);
            short8 bf;
            bf[0]=(short)f2bf(ka.x); bf[1]=(short)f2bf(ka.y); bf[2]=(short)f2bf(ka.z); bf[3]=(short)f2bf(ka.w);
            bf[4]=(short)f2bf(kb.x); bf[5]=(short)f2bf(kb.y); bf[6]=(short)f2bf(kb.z); bf[7]=(short)f2bf(kb.w);
            acc1[t] = __builtin_amdgcn_mfma_f32_16x16x32_bf16(af, bf, acc1[t], 0, 0, 0);
        }
    }
    #pragma unroll
    for (int t = 0; t < 16; ++t) {
        const int col = kw0 + t * 16 + m;
        #pragma unroll
        for (int r = 0; r < 4; ++r)
            p_lds[(quad * 4 + r) * PSTR1 + col] = (short)f2bf(acc1[t][r]);
    }
    __syncthreads();

    {
        const int r  = tid >> 4;
        const int kc = tid & 15;
        const int qg = qt * 16 + r;
        const float rmq = rm_f[qg];
        const float inv_scale = 0.04419417382415922f;

        float4 sv[16];
        float mx = 0.0f;
        #pragma unroll
        for (int j = 0; j < 16; ++j) {
            const int k0 = 4 * kc + 64 * j;
            short4 s4 = *reinterpret_cast<const short4*>(&p_lds[r * PSTR1 + k0]);
            float s0 = bf2f((unsigned short)s4.x) * inv_scale;
            float s1 = bf2f((unsigned short)s4.y) * inv_scale;
            float s2 = bf2f((unsigned short)s4.z) * inv_scale;
            float s3 = bf2f((unsigned short)s4.w) * inv_scale;
            sv[j] = make_float4(s0, s1, s2, s3);
            if (rmq != 0.f) {
                if (rm_f[k0+0] != 0.f && (k0+0) < qg) mx = fmaxf(mx, s0);
                if (rm_f[k0+1] != 0.f && (k0+1) < qg) mx = fmaxf(mx, s1);
                if (rm_f[k0+2] != 0.f && (k0+2) < qg) mx = fmaxf(mx, s2);
                if (rm_f[k0+3] != 0.f && (k0+3) < qg) mx = fmaxf(mx, s3);
            }
        }
        #pragma unroll
        for (int off = 1; off < 16; off <<= 1) mx = fmaxf(mx, __shfl_xor(mx, off));

        float sum = 0.0f;
        #pragma unroll
        for (int j = 0; j < 16; ++j) {
            const int k0 = 4 * kc + 64 * j;
            float p0 = 0.f, p1 = 0.f, p2 = 0.f, p3 = 0.f;
            if (rmq != 0.f) {
                if (rm_f[k0+0] != 0.f && (k0+0) < qg) p0 = __expf(sv[j].x - mx);
                if (rm_f[k0+1] != 0.f && (k0+1) < qg) p1 = __expf(sv[j].y - mx);
                if (rm_f[k0+2] != 0.f && (k0+2) < qg) p2 = __expf(sv[j].z - mx);
                if (rm_f[k0+3] != 0.f && (k0+3) < qg) p3 = __expf(sv[j].w - mx);
            }
            sv[j] = make_float4(p0, p1, p2, p3);
            sum += (p0 + p1) + (p2 + p3);
        }
        #pragma unroll
        for (int off = 1; off < 16; off <<= 1) sum += __shfl_xor(sum, off);

        float den = sum + ((sum == 0.0f) ? 1.0f : 0.0f);
        const float invd = 1.0f / (den + 1e-20f);

        float* arow = Attn + ((size_t)(b * S_) + qg) * S_;
        #pragma unroll
        for (int j = 0; j < 16; ++j) {
            const int k0 = 4 * kc + 64 * j;
            float p0 = sv[j].x * invd, p1 = sv[j].y * invd;
            float p2 = sv[j].z * invd, p3 = sv[j].w * invd;
            *reinterpret_cast<float4*>(arow + k0) = make_float4(p0, p1, p2, p3);
            short4 pb;
            pb.x=(short)f2bf(p0); pb.y=(short)f2bf(p1); pb.z=(short)f2bf(p2); pb.w=(short)f2bf(p3);
            *reinterpret_cast<short4*>(&p_lds[r * PSTR1 + k0]) = pb;
        }
    }
    __syncthreads();

    f32x4 acc2[8];
    #pragma unroll
    for (int i = 0; i < 8; ++i) acc2[i] = (f32x4){0.f, 0.f, 0.f, 0.f};

    for (int kk = 0; kk < 32; ++kk) {
        const short8 af = *reinterpret_cast<const short8*>(
            &p_lds[m * PSTR1 + kk * 32 + quad * 8]);
        #pragma unroll
        for (int nh = 0; nh < 2; ++nh) {
            __syncthreads();
            {
                const int nl0 = tid & 63;
                const int qq0 = tid >> 6;
                #pragma unroll
                for (int i = 0; i < 8; ++i) {
                    const int nl = nl0 + 64 * (i & 3);
                    const int qq = qq0 + 4 * (i >> 2);
                    const float* src = V + ((size_t)(b * S_ + kk * 32 + qq * 4)) * D_
                                         + nh * 256 + nl;
                    const float v0 = src[0];
                    const float v1 = src[D_];
                    const float v2 = src[2 * D_];
                    const float v3 = src[3 * D_];
                    const int g  = (nl >> 1) & 3;
                    const int dw = nl * 16 + 4 * ((qq >> 1) ^ g) + 2 * (qq & 1);
                    short4 pk;
                    pk.x=(short)f2bf(v0); pk.y=(short)f2bf(v1);
                    pk.z=(short)f2bf(v2); pk.w=(short)f2bf(v3);
                    *reinterpret_cast<short4*>(&vt_lds[dw * 2]) = pk;
                }
            }
            __syncthreads();
            #pragma unroll
            for (int f = 0; f < 4; ++f) {
                const int nloc = (w + 4 * f) * 16 + m;
                const int g  = (nloc >> 1) & 3;
                const int dw = nloc * 16 + 4 * (quad ^ g);
                const short8 bf = *reinterpret_cast<const short8*>(&vt_lds[dw * 2]);
                acc2[nh * 4 + f] = __builtin_amdgcn_mfma_f32_16x16x32_bf16(af, bf, acc2[nh * 4 + f], 0, 0, 0);
            }
        }
    }

    float* obase = Out + ((size_t)(b * S_ + qt * 16)) * D_;
    #pragma unroll
    for (int nh = 0; nh < 2; ++nh) {
        #pragma unroll
        for (int f = 0; f < 4; ++f) {
            const int n0 = nh * 256 + (w + 4 * f) * 16 + m;
            #pragma unroll
            for (int r = 0; r < 4; ++r)
                obase[(size_t)(quad * 4 + r) * D_ + n0] = acc2[nh * 4 + f][r];
        }
    }
}

extern "C" void kernel_launch(void* const* d_in, const int* in_sizes, int n_in,
                              void* d_out, int out_size, void* d_ws, size_t ws_size,
                              hipStream_t stream) {
    (void)in_sizes; (void)n_in; (void)out_size;
    const float* q  = (const float*)d_in[0];
    const float* k  = (const float*)d_in[1];
    const float* v  = (const float*)d_in[2];
    const int*   rm = (const int*)d_in[3];
    float* out  = (float*)d_out;
    float* attn = out + (size_t)B_ * S_ * D_;

    const size_t buf_bytes = (size_t)B_ * 524288 * 2;    // 32 MB each
    const size_t need2 = 2 * buf_bytes;                  // KT + VT = 64 MB
    if (ws_size >= need2) {
        unsigned short* KT = (unsigned short*)d_ws;
        unsigned short* VT = KT + (size_t)B_ * 524288;
        prep_k<<<dim3(B_ * 256), dim3(256), 0, stream>>>(k, KT);
        prep_v<<<dim3(B_ * 64), dim3(256), 0, stream>>>(v, VT);
        attn_main32<<<dim3(B_ * (S_ / 32)), dim3(512), 0, stream>>>(q, KT, VT, rm, out, attn);
    } else {
        attn_fused_v1<<<dim3(B_ * (S_ / 16)), dim3(256), 0, stream>>>(q, k, v, rm, out, attn);
    }
}

// Round 5
// 514.506 us; speedup vs baseline: 1.0373x; 1.0239x over previous
//
#include <hip/hip_runtime.h>
#include <hip/hip_bf16.h>

#define B_ 32
#define S_ 1024
#define D_ 512
#define PSTR 1048    // P row stride (bf16 elems)
#define PSTR1 1032   // fallback v1 stride

typedef __attribute__((ext_vector_type(8))) short short8;
typedef __attribute__((ext_vector_type(4))) float f32x4;

__device__ __forceinline__ unsigned short f2bf(float f) {
    unsigned u = __float_as_uint(f);
    u += 0x7FFFu + ((u >> 16) & 1u);   // round-to-nearest-even
    return (unsigned short)(u >> 16);
}
__device__ __forceinline__ float bf2f(unsigned short s) {
    return __uint_as_float(((unsigned)s) << 16);
}

// ===================== merged prep: Q->QB, K->KT, V->VT (one launch) =====================
// QB[b][s][d] bf16 row-major
// KT[b][ds(16)][kcol(1024)][dquad(4)][8]
// VT[b][kk(32)][dcol(512)][kquad(4)][8]  (store coalesced: lane l -> dcol=l>>2, kq=l&3)
__global__ __launch_bounds__(256) void prep_all(const float* __restrict__ Q,
                                                const float* __restrict__ K,
                                                const float* __restrict__ V,
                                                unsigned short* __restrict__ QB,
                                                unsigned short* __restrict__ KT,
                                                unsigned short* __restrict__ VT) {
    const int bid = blockIdx.x;
    if (bid < 8192) {
        // ---- Q -> QB bf16 ----
        const size_t i = ((size_t)bid * 256 + threadIdx.x) * 8;
        const float4 a = *reinterpret_cast<const float4*>(Q + i);
        const float4 c = *reinterpret_cast<const float4*>(Q + i + 4);
        short8 p;
        p[0]=(short)f2bf(a.x); p[1]=(short)f2bf(a.y); p[2]=(short)f2bf(a.z); p[3]=(short)f2bf(a.w);
        p[4]=(short)f2bf(c.x); p[5]=(short)f2bf(c.y); p[6]=(short)f2bf(c.z); p[7]=(short)f2bf(c.w);
        *reinterpret_cast<short8*>(QB + i) = p;
    } else if (bid < 16384) {
        // ---- K -> KT ----
        const int blk = bid - 8192;      // 32*256 blocks: 4 rows x 512 d each
        const int b  = blk >> 8;
        const int r4 = blk & 255;
        const int t  = threadIdx.x;
        const int r  = t >> 6;           // 0..3
        const int d0 = (t & 63) * 8;
        const int s  = r4 * 4 + r;
        const float* src = K + ((size_t)(b * S_ + s)) * D_ + d0;
        const float4 a = *reinterpret_cast<const float4*>(src);
        const float4 c = *reinterpret_cast<const float4*>(src + 4);
        const int ds = d0 >> 5, dq = (d0 >> 3) & 3;
        short8 p;
        p[0]=(short)f2bf(a.x); p[1]=(short)f2bf(a.y); p[2]=(short)f2bf(a.z); p[3]=(short)f2bf(a.w);
        p[4]=(short)f2bf(c.x); p[5]=(short)f2bf(c.y); p[6]=(short)f2bf(c.z); p[7]=(short)f2bf(c.w);
        unsigned short* dst = KT + (size_t)b * 524288 + (((ds * 1024 + s) * 4 + dq) * 8);
        *reinterpret_cast<short8*>(dst) = p;
    } else {
        // ---- V -> VT ----
        __shared__ float st[32 * 261];   // pad 261: LDS read conflicts <= 2-way
        const int blk = bid - 16384;     // 32*32*2 blocks
        const int b  = blk >> 6;
        const int kk = (blk >> 1) & 31;
        const int dh = blk & 1;
        const int t  = threadIdx.x;
        const int r0 = t >> 6;
        const int c4 = (t & 63) * 4;
        #pragma unroll
        for (int p = 0; p < 8; ++p) {
            const int s = r0 + p * 4;
            const float4 val = *reinterpret_cast<const float4*>(
                V + ((size_t)(b * S_ + kk * 32 + s)) * D_ + dh * 256 + c4);
            *reinterpret_cast<float4*>(&st[s * 261 + c4]) = val;
        }
        __syncthreads();
        const int kq = t & 3;
        #pragma unroll
        for (int pass = 0; pass < 4; ++pass) {
            const int dcol = (t >> 2) + pass * 64;   // local 0..255
            short8 p;
            #pragma unroll
            for (int j = 0; j < 8; ++j) p[j] = (short)f2bf(st[(kq * 8 + j) * 261 + dcol]);
            unsigned short* dst = VT + (size_t)b * 524288
                + (((size_t)(kk * 512 + dh * 256 + dcol) * 4 + kq) * 8);
            *reinterpret_cast<short8*>(dst) = p;
        }
    }
}

// standalone preps for the 64MB-workspace fallback path
__global__ __launch_bounds__(256) void prep_k(const float* __restrict__ K,
                                              unsigned short* __restrict__ KT) {
    const int blk = blockIdx.x;
    const int b  = blk >> 8;
    const int r4 = blk & 255;
    const int t  = threadIdx.x;
    const int r  = t >> 6;
    const int d0 = (t & 63) * 8;
    const int s  = r4 * 4 + r;
    const float* src = K + ((size_t)(b * S_ + s)) * D_ + d0;
    const float4 a = *reinterpret_cast<const float4*>(src);
    const float4 c = *reinterpret_cast<const float4*>(src + 4);
    const int ds = d0 >> 5, dq = (d0 >> 3) & 3;
    short8 p;
    p[0]=(short)f2bf(a.x); p[1]=(short)f2bf(a.y); p[2]=(short)f2bf(a.z); p[3]=(short)f2bf(a.w);
    p[4]=(short)f2bf(c.x); p[5]=(short)f2bf(c.y); p[6]=(short)f2bf(c.z); p[7]=(short)f2bf(c.w);
    unsigned short* dst = KT + (size_t)b * 524288 + (((ds * 1024 + s) * 4 + dq) * 8);
    *reinterpret_cast<short8*>(dst) = p;
}

__global__ __launch_bounds__(256) void prep_v(const float* __restrict__ V,
                                              unsigned short* __restrict__ VT) {
    __shared__ float st[32 * 261];
    const int blk = blockIdx.x;
    const int b  = blk >> 6;
    const int kk = (blk >> 1) & 31;
    const int dh = blk & 1;
    const int t  = threadIdx.x;
    const int r0 = t >> 6;
    const int c4 = (t & 63) * 4;
    #pragma unroll
    for (int p = 0; p < 8; ++p) {
        const int s = r0 + p * 4;
        const float4 val = *reinterpret_cast<const float4*>(
            V + ((size_t)(b * S_ + kk * 32 + s)) * D_ + dh * 256 + c4);
        *reinterpret_cast<float4*>(&st[s * 261 + c4]) = val;
    }
    __syncthreads();
    const int kq = t & 3;
    #pragma unroll
    for (int pass = 0; pass < 4; ++pass) {
        const int dcol = (t >> 2) + pass * 64;
        short8 p;
        #pragma unroll
        for (int j = 0; j < 8; ++j) p[j] = (short)f2bf(st[(kq * 8 + j) * 261 + dcol]);
        unsigned short* dst = VT + (size_t)b * 524288
            + (((size_t)(kk * 512 + dh * 256 + dcol) * 4 + kq) * 8);
        *reinterpret_cast<short8*>(dst) = p;
    }
}

// ===================== main fused kernel: 32 q-rows / block, 8 waves (R2 structure + NT stores) =====================
__global__ __launch_bounds__(512, 4)
void attn_main32(const unsigned short* __restrict__ QB, const unsigned short* __restrict__ KT,
                 const unsigned short* __restrict__ VT, const int* __restrict__ RM,
                 float* __restrict__ Out, float* __restrict__ Attn) {
    __shared__ short p_lds[32 * PSTR];   // 67072 B
    __shared__ float rm_f[1024];         // 4096 B  -> 2 blocks/CU

    const int tid  = threadIdx.x;
    const int lane = tid & 63;
    const int w    = tid >> 6;           // 0..7
    const int m    = lane & 15;
    const int quad = lane >> 4;

    const int work = ((int)blockIdx.x & 7) * 128 + ((int)blockIdx.x >> 3);
    const int b  = work >> 5;
    const int qt = work & 31;

    {
        const int2 mi = *reinterpret_cast<const int2*>(RM + b * S_ + tid * 2);
        rm_f[tid * 2]     = (float)mi.x;
        rm_f[tid * 2 + 1] = (float)mi.y;
    }

    // ---------------- Phase 1: raw scores = Q K^T ----------------
    f32x4 acc1[2][8];
    #pragma unroll
    for (int mt = 0; mt < 2; ++mt)
        #pragma unroll
        for (int t = 0; t < 8; ++t) acc1[mt][t] = (f32x4){0.f, 0.f, 0.f, 0.f};

    const unsigned short* qb0 = QB + (size_t)b * (S_ * D_) + (size_t)(qt * 32 + m) * D_ + quad * 8;
    const unsigned short* qb1 = qb0 + 16 * D_;
    const unsigned short* kb  = KT + (size_t)b * 524288 + (w * 128 + m) * 32 + quad * 8;

    for (int ds = 0; ds < 16; ++ds) {
        const short8 a0 = *reinterpret_cast<const short8*>(qb0 + ds * 32);
        const short8 a1 = *reinterpret_cast<const short8*>(qb1 + ds * 32);
        const unsigned short* kds = kb + ds * 32768;
        #pragma unroll
        for (int t = 0; t < 8; ++t) {
            const short8 bf = *reinterpret_cast<const short8*>(kds + t * 512);
            acc1[0][t] = __builtin_amdgcn_mfma_f32_16x16x32_bf16(a0, bf, acc1[0][t], 0, 0, 0);
            acc1[1][t] = __builtin_amdgcn_mfma_f32_16x16x32_bf16(a1, bf, acc1[1][t], 0, 0, 0);
        }
    }
    #pragma unroll
    for (int mt = 0; mt < 2; ++mt)
        #pragma unroll
        for (int t = 0; t < 8; ++t) {
            const int col = w * 128 + t * 16 + m;
            #pragma unroll
            for (int r = 0; r < 4; ++r)
                p_lds[(mt * 16 + quad * 4 + r) * PSTR + col] = (short)f2bf(acc1[mt][t][r]);
        }
    __syncthreads();

    // ---------------- softmax (reference-faithful masked variant) ----------------
    {
        const int r  = tid >> 4;          // 0..31
        const int kc = tid & 15;
        const int qg = qt * 32 + r;
        const float rmq = rm_f[qg];
        const float inv_scale = 0.04419417382415922f;   // 1/sqrt(512)

        float4 sv[16];
        float mx = 0.0f;
        #pragma unroll
        for (int j = 0; j < 16; ++j) {
            const int k0 = 4 * kc + 64 * j;
            short4 s4 = *reinterpret_cast<const short4*>(&p_lds[r * PSTR + k0]);
            const float4 rmk = *reinterpret_cast<const float4*>(&rm_f[k0]);
            float s0 = bf2f((unsigned short)s4.x) * inv_scale;
            float s1 = bf2f((unsigned short)s4.y) * inv_scale;
            float s2 = bf2f((unsigned short)s4.z) * inv_scale;
            float s3 = bf2f((unsigned short)s4.w) * inv_scale;
            sv[j] = make_float4(s0, s1, s2, s3);
            if (rmq != 0.f) {
                if (rmk.x != 0.f && (k0+0) < qg) mx = fmaxf(mx, s0);
                if (rmk.y != 0.f && (k0+1) < qg) mx = fmaxf(mx, s1);
                if (rmk.z != 0.f && (k0+2) < qg) mx = fmaxf(mx, s2);
                if (rmk.w != 0.f && (k0+3) < qg) mx = fmaxf(mx, s3);
            }
        }
        #pragma unroll
        for (int off = 1; off < 16; off <<= 1) mx = fmaxf(mx, __shfl_xor(mx, off));

        float sum = 0.0f;
        #pragma unroll
        for (int j = 0; j < 16; ++j) {
            const int k0 = 4 * kc + 64 * j;
            const float4 rmk = *reinterpret_cast<const float4*>(&rm_f[k0]);
            float p0 = 0.f, p1 = 0.f, p2 = 0.f, p3 = 0.f;
            if (rmq != 0.f) {
                if (rmk.x != 0.f && (k0+0) < qg) p0 = __expf(sv[j].x - mx);
                if (rmk.y != 0.f && (k0+1) < qg) p1 = __expf(sv[j].y - mx);
                if (rmk.z != 0.f && (k0+2) < qg) p2 = __expf(sv[j].z - mx);
                if (rmk.w != 0.f && (k0+3) < qg) p3 = __expf(sv[j].w - mx);
            }
            sv[j] = make_float4(p0, p1, p2, p3);
            sum += (p0 + p1) + (p2 + p3);
        }
        #pragma unroll
        for (int off = 1; off < 16; off <<= 1) sum += __shfl_xor(sum, off);

        float den = sum + ((sum == 0.0f) ? 1.0f : 0.0f);
        const float invd = 1.0f / (den + 1e-20f);

        float* arow = Attn + ((size_t)(b * S_) + qg) * S_;
        #pragma unroll
        for (int j = 0; j < 16; ++j) {
            const int k0 = 4 * kc + 64 * j;
            float p0 = sv[j].x * invd, p1 = sv[j].y * invd;
            float p2 = sv[j].z * invd, p3 = sv[j].w * invd;
            f32x4 pv = {p0, p1, p2, p3};
            __builtin_nontemporal_store(pv, reinterpret_cast<f32x4*>(arow + k0));
            short4 pb;
            pb.x=(short)f2bf(p0); pb.y=(short)f2bf(p1); pb.z=(short)f2bf(p2); pb.w=(short)f2bf(p3);
            *reinterpret_cast<short4*>(&p_lds[r * PSTR + k0]) = pb;
        }
    }
    __syncthreads();

    // ---------------- Phase 2: Out = P V ----------------
    f32x4 acc2[2][4];
    #pragma unroll
    for (int mt = 0; mt < 2; ++mt)
        #pragma unroll
        for (int f = 0; f < 4; ++f) acc2[mt][f] = (f32x4){0.f, 0.f, 0.f, 0.f};

    const unsigned short* vb = VT + (size_t)b * 524288 + m * 32 + quad * 8;
    for (int kk = 0; kk < 32; ++kk) {
        const short8 af0 = *reinterpret_cast<const short8*>(
            &p_lds[m * PSTR + kk * 32 + quad * 8]);
        const short8 af1 = *reinterpret_cast<const short8*>(
            &p_lds[(16 + m) * PSTR + kk * 32 + quad * 8]);
        const unsigned short* vkk = vb + kk * 16384;
        #pragma unroll
        for (int f = 0; f < 4; ++f) {
            const short8 bf = *reinterpret_cast<const short8*>(vkk + (w * 4 + f) * 512);
            acc2[0][f] = __builtin_amdgcn_mfma_f32_16x16x32_bf16(af0, bf, acc2[0][f], 0, 0, 0);
            acc2[1][f] = __builtin_amdgcn_mfma_f32_16x16x32_bf16(af1, bf, acc2[1][f], 0, 0, 0);
        }
    }

    float* obase = Out + ((size_t)(b * S_ + qt * 32)) * D_;
    #pragma unroll
    for (int mt = 0; mt < 2; ++mt)
        #pragma unroll
        for (int f = 0; f < 4; ++f) {
            const int n0 = (w * 4 + f) * 16 + m;
            #pragma unroll
            for (int r = 0; r < 4; ++r)
                __builtin_nontemporal_store(acc2[mt][f][r],
                    &obase[(size_t)(mt * 16 + quad * 4 + r) * D_ + n0]);
        }
}

// ===================== fallback: 16-row main (needs only KT+VT, 64 MB) =====================
__global__ __launch_bounds__(256, 4)
void attn_main(const float* __restrict__ Q, const unsigned short* __restrict__ KT,
               const unsigned short* __restrict__ VT, const int* __restrict__ RM,
               float* __restrict__ Out, float* __restrict__ Attn) {
    __shared__ short p_lds[16 * PSTR];
    __shared__ float rm_f[1024];

    const int tid  = threadIdx.x;
    const int lane = tid & 63;
    const int w    = tid >> 6;
    const int m    = lane & 15;
    const int quad = lane >> 4;

    const int work = ((int)blockIdx.x & 7) * 256 + ((int)blockIdx.x >> 3);
    const int b  = work >> 6;
    const int qt = work & 63;

    {
        const int4 mi = *reinterpret_cast<const int4*>(RM + b * S_ + tid * 4);
        float4 mf = make_float4((float)mi.x, (float)mi.y, (float)mi.z, (float)mi.w);
        *reinterpret_cast<float4*>(&rm_f[tid * 4]) = mf;
    }

    f32x4 acc1[16];
    #pragma unroll
    for (int t = 0; t < 16; ++t) acc1[t] = (f32x4){0.f, 0.f, 0.f, 0.f};

    const int kw0 = w * 256;
    const float* qbase = Q + ((size_t)(b * S_ + qt * 16 + m)) * D_ + quad * 8;
    const unsigned short* kb = KT + (size_t)b * 524288 + (kw0 + m) * 32 + quad * 8;

    for (int ds = 0; ds < 16; ++ds) {
        const float4 qa = *reinterpret_cast<const float4*>(qbase + ds * 32);
        const float4 qb = *reinterpret_cast<const float4*>(qbase + ds * 32 + 4);
        short8 af;
        af[0]=(short)f2bf(qa.x); af[1]=(short)f2bf(qa.y); af[2]=(short)f2bf(qa.z); af[3]=(short)f2bf(qa.w);
        af[4]=(short)f2bf(qb.x); af[5]=(short)f2bf(qb.y); af[6]=(short)f2bf(qb.z); af[7]=(short)f2bf(qb.w);
        const unsigned short* kds = kb + ds * 32768;
        #pragma unroll
        for (int t = 0; t < 16; ++t) {
            const short8 bf = *reinterpret_cast<const short8*>(kds + t * 512);
            acc1[t] = __builtin_amdgcn_mfma_f32_16x16x32_bf16(af, bf, acc1[t], 0, 0, 0);
        }
    }
    #pragma unroll
    for (int t = 0; t < 16; ++t) {
        const int col = kw0 + t * 16 + m;
        #pragma unroll
        for (int r = 0; r < 4; ++r)
            p_lds[(quad * 4 + r) * PSTR + col] = (short)f2bf(acc1[t][r]);
    }
    __syncthreads();

    {
        const int r  = tid >> 4;
        const int kc = tid & 15;
        const int qg = qt * 16 + r;
        const float rmq = rm_f[qg];
        const float inv_scale = 0.04419417382415922f;

        float4 sv[16];
        float mx = 0.0f;
        #pragma unroll
        for (int j = 0; j < 16; ++j) {
            const int k0 = 4 * kc + 64 * j;
            short4 s4 = *reinterpret_cast<const short4*>(&p_lds[r * PSTR + k0]);
            const float4 rmk = *reinterpret_cast<const float4*>(&rm_f[k0]);
            float s0 = bf2f((unsigned short)s4.x) * inv_scale;
            float s1 = bf2f((unsigned short)s4.y) * inv_scale;
            float s2 = bf2f((unsigned short)s4.z) * inv_scale;
            float s3 = bf2f((unsigned short)s4.w) * inv_scale;
            sv[j] = make_float4(s0, s1, s2, s3);
            if (rmq != 0.f) {
                if (rmk.x != 0.f && (k0+0) < qg) mx = fmaxf(mx, s0);
                if (rmk.y != 0.f && (k0+1) < qg) mx = fmaxf(mx, s1);
                if (rmk.z != 0.f && (k0+2) < qg) mx = fmaxf(mx, s2);
                if (rmk.w != 0.f && (k0+3) < qg) mx = fmaxf(mx, s3);
            }
        }
        #pragma unroll
        for (int off = 1; off < 16; off <<= 1) mx = fmaxf(mx, __shfl_xor(mx, off));

        float sum = 0.0f;
        #pragma unroll
        for (int j = 0; j < 16; ++j) {
            const int k0 = 4 * kc + 64 * j;
            const float4 rmk = *reinterpret_cast<const float4*>(&rm_f[k0]);
            float p0 = 0.f, p1 = 0.f, p2 = 0.f, p3 = 0.f;
            if (rmq != 0.f) {
                if (rmk.x != 0.f && (k0+0) < qg) p0 = __expf(sv[j].x - mx);
                if (rmk.y != 0.f && (k0+1) < qg) p1 = __expf(sv[j].y - mx);
                if (rmk.z != 0.f && (k0+2) < qg) p2 = __expf(sv[j].z - mx);
                if (rmk.w != 0.f && (k0+3) < qg) p3 = __expf(sv[j].w - mx);
            }
            sv[j] = make_float4(p0, p1, p2, p3);
            sum += (p0 + p1) + (p2 + p3);
        }
        #pragma unroll
        for (int off = 1; off < 16; off <<= 1) sum += __shfl_xor(sum, off);

        float den = sum + ((sum == 0.0f) ? 1.0f : 0.0f);
        const float invd = 1.0f / (den + 1e-20f);

        float* arow = Attn + ((size_t)(b * S_) + qg) * S_;
        #pragma unroll
        for (int j = 0; j < 16; ++j) {
            const int k0 = 4 * kc + 64 * j;
            float p0 = sv[j].x * invd, p1 = sv[j].y * invd;
            float p2 = sv[j].z * invd, p3 = sv[j].w * invd;
            *reinterpret_cast<float4*>(arow + k0) = make_float4(p0, p1, p2, p3);
            short4 pb;
            pb.x=(short)f2bf(p0); pb.y=(short)f2bf(p1); pb.z=(short)f2bf(p2); pb.w=(short)f2bf(p3);
            *reinterpret_cast<short4*>(&p_lds[r * PSTR + k0]) = pb;
        }
    }
    __syncthreads();

    f32x4 acc2[8];
    #pragma unroll
    for (int i = 0; i < 8; ++i) acc2[i] = (f32x4){0.f, 0.f, 0.f, 0.f};

    const unsigned short* vb = VT + (size_t)b * 524288 + m * 32 + quad * 8;
    for (int kk = 0; kk < 32; ++kk) {
        const short8 af = *reinterpret_cast<const short8*>(
            &p_lds[m * PSTR + kk * 32 + quad * 8]);
        const unsigned short* vkk = vb + kk * 16384;
        #pragma unroll
        for (int f = 0; f < 8; ++f) {
            const int dtile = f * 4 + w;
            const short8 bf = *reinterpret_cast<const short8*>(vkk + dtile * 512);
            acc2[f] = __builtin_amdgcn_mfma_f32_16x16x32_bf16(af, bf, acc2[f], 0, 0, 0);
        }
    }

    float* obase = Out + ((size_t)(b * S_ + qt * 16)) * D_;
    #pragma unroll
    for (int f = 0; f < 8; ++f) {
        const int n0 = (f * 4 + w) * 16 + m;
        #pragma unroll
        for (int r = 0; r < 4; ++r)
            obase[(size_t)(quad * 4 + r) * D_ + n0] = acc2[f][r];
    }
}

// ===================== fallback v1 (used only if ws too small) =====================
__global__ __launch_bounds__(256, 3)
void attn_fused_v1(const float* __restrict__ Q, const float* __restrict__ K,
                   const float* __restrict__ V, const int* __restrict__ RM,
                   float* __restrict__ Out, float* __restrict__ Attn) {
    __shared__ short p_lds[16 * PSTR1];
    __shared__ short vt_lds[8192];
    float* rm_f = reinterpret_cast<float*>(vt_lds);

    const int tid  = threadIdx.x;
    const int lane = tid & 63;
    const int w    = tid >> 6;
    const int m    = lane & 15;
    const int quad = lane >> 4;

    const int work = ((int)blockIdx.x & 7) * 256 + ((int)blockIdx.x >> 3);
    const int b  = work >> 6;
    const int qt = work & 63;

    {
        const int4 mi = *reinterpret_cast<const int4*>(RM + b * S_ + tid * 4);
        float4 mf = make_float4((float)mi.x, (float)mi.y, (float)mi.z, (float)mi.w);
        *reinterpret_cast<float4*>(&rm_f[tid * 4]) = mf;
    }

    f32x4 acc1[16];
    #pragma unroll
    for (int t = 0; t < 16; ++t) acc1[t] = (f32x4){0.f, 0.f, 0.f, 0.f};

    const int kw0 = w * 256;
    const float* qbase = Q + ((size_t)(b * S_ + qt * 16 + m)) * D_ + quad * 8;
    const float* kbase = K + ((size_t)(b * S_ + kw0 + m)) * D_ + quad * 8;

    for (int ds = 0; ds < 16; ++ds) {
        const float4 qa = *reinterpret_cast<const float4*>(qbase + ds * 32);
        const float4 qb = *reinterpret_cast<const float4*>(qbase + ds * 32 + 4);
        short8 af;
        af[0]=(short)f2bf(qa.x); af[1]=(short)f2bf(qa.y); af[2]=(short)f2bf(qa.z); af[3]=(short)f2bf(qa.w);
        af[4]=(short)f2bf(qb.x); af[5]=(short)f2bf(qb.y); af[6]=(short)f2bf(qb.z); af[7]=(short)f2bf(qb.w);
        #pragma unroll
        for (int t = 0; t < 16; ++t) {
            const float* kr = kbase + (size_t)t * 16 * D_ + ds * 32;
            const float4 ka = *reinterpret_cast<const float4*>(kr);
            const float4 kb = *reinterpret_cast<const float4*>(kr + 4);
            short8 bf;
            bf[0]=(short)f2bf(ka.x); bf[1]=(short)f2bf(ka.y); bf[2]=(short)f2bf(ka.z); bf[3]=(short)f2bf(ka.w);
            bf[4]=(short)f2bf(kb.x); bf[5]=(short)f2bf(kb.y); bf[6]=(short)f2bf(kb.z); bf[7]=(short)f2bf(kb.w);
            acc1[t] = __builtin_amdgcn_mfma_f32_16x16x32_bf16(af, bf, acc1[t], 0, 0, 0);
        }
    }
    #pragma unroll
    for (int t = 0; t < 16; ++t) {
        const int col = kw0 + t * 16 + m;
        #pragma unroll
        for (int r = 0; r < 4; ++r)
            p_lds[(quad * 4 + r) * PSTR1 + col] = (short)f2bf(acc1[t][r]);
    }
    __syncthreads();

    {
        const int r  = tid >> 4;
        const int kc = tid & 15;
        const int qg = qt * 16 + r;
        const float rmq = rm_f[qg];
        const float inv_scale = 0.04419417382415922f;

        float4 sv[16];
        float mx = 0.0f;
        #pragma unroll
        for (int j = 0; j < 16; ++j) {
            const int k0 = 4 * kc + 64 * j;
            short4 s4 = *reinterpret_cast<const short4*>(&p_lds[r * PSTR1 + k0]);
            float s0 = bf2f((unsigned short)s4.x) * inv_scale;
            float s1 = bf2f((unsigned short)s4.y) * inv_scale;
            float s2 = bf2f((unsigned short)s4.z) * inv_scale;
            float s3 = bf2f((unsigned short)s4.w) * inv_scale;
            sv[j] = make_float4(s0, s1, s2, s3);
            if (rmq != 0.f) {
                if (rm_f[k0+0] != 0.f && (k0+0) < qg) mx = fmaxf(mx, s0);
                if (rm_f[k0+1] != 0.f && (k0+1) < qg) mx = fmaxf(mx, s1);
                if (rm_f[k0+2] != 0.f && (k0+2) < qg) mx = fmaxf(mx, s2);
                if (rm_f[k0+3] != 0.f && (k0+3) < qg) mx = fmaxf(mx, s3);
            }
        }
        #pragma unroll
        for (int off = 1; off < 16; off <<= 1) mx = fmaxf(mx, __shfl_xor(mx, off));

        float sum = 0.0f;
        #pragma unroll
        for (int j = 0; j < 16; ++j) {
            const int k0 = 4 * kc + 64 * j;
            float p0 = 0.f, p1 = 0.f, p2 = 0.f, p3 = 0.f;
            if (rmq != 0.f) {
                if (rm_f[k0+0] != 0.f && (k0+0) < qg) p0 = __expf(sv[j].x - mx);
                if (rm_f[k0+1] != 0.f && (k0+1) < qg) p1 = __expf(sv[j].y - mx);
                if (rm_f[k0+2] != 0.f && (k0+2) < qg) p2 = __expf(sv[j].z - mx);
                if (rm_f[k0+3] != 0.f && (k0+3) < qg) p3 = __expf(sv[j].w - mx);
            }
            sv[j] = make_float4(p0, p1, p2, p3);
            sum += (p0 + p1) + (p2 + p3);
        }
        #pragma unroll
        for (int off = 1; off < 16; off <<= 1) sum += __shfl_xor(sum, off);

        float den = sum + ((sum == 0.0f) ? 1.0f : 0.0f);
        const float invd = 1.0f / (den + 1e-20f);

        float* arow = Attn + ((size_t)(b * S_) + qg) * S_;
        #pragma unroll
        for (int j = 0; j < 16; ++j) {
            const int k0 = 4 * kc + 64 * j;
            float p0 = sv[j].x * invd, p1 = sv[j].y * invd;
            float p2 = sv[j].z * invd, p3 = sv[j].w * invd;
            *reinterpret_cast<float4*>(arow + k0) = make_float4(p0, p1, p2, p3);
            short4 pb;
            pb.x=(short)f2bf(p0); pb.y=(short)f2bf(p1); pb.z=(short)f2bf(p2); pb.w=(short)f2bf(p3);
            *reinterpret_cast<short4*>(&p_lds[r * PSTR1 + k0]) = pb;
        }
    }
    __syncthreads();

    f32x4 acc2[8];
    #pragma unroll
    for (int i = 0; i < 8; ++i) acc2[i] = (f32x4){0.f, 0.f, 0.f, 0.f};

    for (int kk = 0; kk < 32; ++kk) {
        const short8 af = *reinterpret_cast<const short8*>(
            &p_lds[m * PSTR1 + kk * 32 + quad * 8]);
        #pragma unroll
        for (int nh = 0; nh < 2; ++nh) {
            __syncthreads();
            {
                const int nl0 = tid & 63;
                const int qq0 = tid >> 6;
                #pragma unroll
                for (int i = 0; i < 8; ++i) {
                    const int nl = nl0 + 64 * (i & 3);
                    const int qq = qq0 + 4 * (i >> 2);
                    const float* src = V + ((size_t)(b * S_ + kk * 32 + qq * 4)) * D_
                                         + nh * 256 + nl;
                    const float v0 = src[0];
                    const float v1 = src[D_];
                    const float v2 = src[2 * D_];
                    const float v3 = src[3 * D_];
                    const int g  = (nl >> 1) & 3;
                    const int dw = nl * 16 + 4 * ((qq >> 1) ^ g) + 2 * (qq & 1);
                    short4 pk;
                    pk.x=(short)f2bf(v0); pk.y=(short)f2bf(v1);
                    pk.z=(short)f2bf(v2); pk.w=(short)f2bf(v3);
                    *reinterpret_cast<short4*>(&vt_lds[dw * 2]) = pk;
                }
            }
            __syncthreads();
            #pragma unroll
            for (int f = 0; f < 4; ++f) {
                const int nloc = (w + 4 * f) * 16 + m;
                const int g  = (nloc >> 1) & 3;
                const int dw = nloc * 16 + 4 * (quad ^ g);
                const short8 bf = *reinterpret_cast<const short8*>(&vt_lds[dw * 2]);
                acc2[nh * 4 + f] = __builtin_amdgcn_mfma_f32_16x16x32_bf16(af, bf, acc2[nh * 4 + f], 0, 0, 0);
            }
        }
    }

    float* obase = Out + ((size_t)(b * S_ + qt * 16)) * D_;
    #pragma unroll
    for (int nh = 0; nh < 2; ++nh) {
        #pragma unroll
        for (int f = 0; f < 4; ++f) {
            const int n0 = nh * 256 + (w + 4 * f) * 16 + m;
            #pragma unroll
            for (int r = 0; r < 4; ++r)
                obase[(size_t)(quad * 4 + r) * D_ + n0] = acc2[nh * 4 + f][r];
        }
    }
}

extern "C" void kernel_launch(void* const* d_in, const int* in_sizes, int n_in,
                              void* d_out, int out_size, void* d_ws, size_t ws_size,
                              hipStream_t stream) {
    (void)in_sizes; (void)n_in; (void)out_size;
    const float* q  = (const float*)d_in[0];
    const float* k  = (const float*)d_in[1];
    const float* v  = (const float*)d_in[2];
    const int*   rm = (const int*)d_in[3];
    float* out  = (float*)d_out;
    float* attn = out + (size_t)B_ * S_ * D_;

    const size_t buf_bytes = (size_t)B_ * 524288 * 2;    // 32 MB each
    const size_t need3 = 3 * buf_bytes;                  // KT + VT + QB = 96 MB
    const size_t need2 = 2 * buf_bytes;                  // KT + VT = 64 MB
    if (ws_size >= need3) {
        unsigned short* KT = (unsigned short*)d_ws;
        unsigned short* VT = KT + (size_t)B_ * 524288;
        unsigned short* QB = VT + (size_t)B_ * 524288;
        prep_all<<<dim3(18432), dim3(256), 0, stream>>>(q, k, v, QB, KT, VT);
        attn_main32<<<dim3(B_ * (S_ / 32)), dim3(512), 0, stream>>>(QB, KT, VT, rm, out, attn);
    } else if (ws_size >= need2) {
        unsigned short* KT = (unsigned short*)d_ws;
        unsigned short* VT = KT + (size_t)B_ * 524288;
        prep_k<<<dim3(B_ * 256), dim3(256), 0, stream>>>(k, KT);
        prep_v<<<dim3(B_ * 64), dim3(256), 0, stream>>>(v, VT);
        attn_main<<<dim3(B_ * (S_ / 16)), dim3(256), 0, stream>>>(q, KT, VT, rm, out, attn);
    } else {
        attn_fused_v1<<<dim3(B_ * (S_ / 16)), dim3(256), 0, stream>>>(q, k, v, rm, out, attn);
    }
}